// Round 7
// baseline (871.312 us; speedup 1.0000x reference)
//
#include <hip/hip_runtime.h>
#include <stdint.h>

// Problem constants (fixed by reference)
#define B_   16
#define S_   2048
#define DIN  512
#define DH   1024
#define DOUT 10

typedef unsigned short u16;
typedef unsigned int   u32;

typedef __bf16 bf16_t;
typedef bf16_t bf16x8 __attribute__((ext_vector_type(8)));
typedef float  f32x4  __attribute__((ext_vector_type(4)));

#define MASKVAL (-3.0e4f)

__device__ __forceinline__ float b2f(u16 u) {
    union { u32 i; float f; } v; v.i = ((u32)u) << 16; return v.f;
}
__device__ __forceinline__ u16 f2b(float f) {
    union { float f; u32 i; } v; v.f = f;
    u32 u = v.i;
    u32 r = (u + 0x7FFFu + ((u >> 16) & 1u)) >> 16;  // RNE
    return (u16)r;
}
__device__ __forceinline__ u32 pack2(float a, float b) {
    return (u32)f2b(a) | ((u32)f2b(b) << 16);
}

__device__ __forceinline__ f32x4 mfma16(bf16x8 a, bf16x8 b, f32x4 c) {
    return __builtin_amdgcn_mfma_f32_16x16x32_bf16(a, b, c, 0, 0, 0);
}

// async global->LDS, 16B per lane; LDS dest = wave-uniform base + lane*16
__device__ __forceinline__ void load_lds16(const u16* g, u16* l) {
    __builtin_amdgcn_global_load_lds(
        (__attribute__((address_space(1))) u32*)(g),
        (__attribute__((address_space(3))) u32*)(l), 16, 0, 0);
}

// load 8 contiguous elements at element-index eidx as packed bf16x8 (uint4)
template<bool F32>
__device__ __forceinline__ uint4 ld8(const void* base, size_t eidx) {
    if constexpr (F32) {
        const float* p = (const float*)base + eidx;
        float4 f0 = *(const float4*)p;
        float4 f1 = *(const float4*)(p + 4);
        uint4 r;
        r.x = pack2(f0.x, f0.y); r.y = pack2(f0.z, f0.w);
        r.z = pack2(f1.x, f1.y); r.w = pack2(f1.z, f1.w);
        return r;
    } else {
        return *(const uint4*)((const u16*)base + eidx);
    }
}

// ---------------------------------------------------------------------------
// f32 -> bf16 elementwise convert (8 elems/thread)
// ---------------------------------------------------------------------------
__global__ __launch_bounds__(256) void cvt_f32_bf16(
    const float* __restrict__ in, u16* __restrict__ out, int n8)
{
    int i = blockIdx.x * 256 + threadIdx.x;
    if (i >= n8) return;
    size_t e = (size_t)i * 8;
    float4 f0 = *(const float4*)(in + e);
    float4 f1 = *(const float4*)(in + e + 4);
    uint4 r;
    r.x = pack2(f0.x, f0.y); r.y = pack2(f0.z, f0.w);
    r.z = pack2(f1.x, f1.y); r.w = pack2(f1.z, f1.w);
    *(uint4*)(out + e) = r;
}

// ---------------------------------------------------------------------------
// ASYNC-staged GEMM: C[M,N] = relu(A[M,K] @ Bt[N,K]^T + bias[N]), all bf16.
// m97 structure: global_load_lds width-16, 128x128 tile, BK=32.
// grid: x = N/128 (fast dim -> concurrent blocks share A rows in L2), y = M/128.
// ---------------------------------------------------------------------------
__global__ __launch_bounds__(256) void gemm_a(
    const u16* __restrict__ A, const u16* __restrict__ Bt,
    const float* __restrict__ bias, u16* __restrict__ C,
    int M, int N, int K, int do_relu)
{
    __shared__ __attribute__((aligned(16))) u16 As[128 * 32];
    __shared__ __attribute__((aligned(16))) u16 Bs[128 * 32];

    const int tid  = threadIdx.x;
    const int lane = tid & 63;
    const int w    = tid >> 6;
    const int wm   = w >> 1, wn = w & 1;
    const int quad = lane >> 4, l15 = lane & 15;

    const int n0 = blockIdx.x * 128;
    const int m0 = blockIdx.y * 128;

    const int c0 = tid, c1 = tid + 256;
    const u16* gA0 = A  + ((size_t)(m0 + (c0 >> 2)) * K + (c0 & 3) * 8);
    const u16* gA1 = A  + ((size_t)(m0 + (c1 >> 2)) * K + (c1 & 3) * 8);
    const u16* gB0 = Bt + ((size_t)(n0 + (c0 >> 2)) * K + (c0 & 3) * 8);
    const u16* gB1 = Bt + ((size_t)(n0 + (c1 >> 2)) * K + (c1 & 3) * 8);
    u16* lA0 = &As[(w * 64) * 8];
    u16* lA1 = &As[(256 + w * 64) * 8];
    u16* lB0 = &Bs[(w * 64) * 8];
    u16* lB1 = &Bs[(256 + w * 64) * 8];

    f32x4 acc[4][4];
#pragma unroll
    for (int i = 0; i < 4; ++i)
#pragma unroll
        for (int j = 0; j < 4; ++j) acc[i][j] = (f32x4){0.f, 0.f, 0.f, 0.f};

    const int nk = K >> 5;
    for (int kk = 0; kk < nk; ++kk) {
        load_lds16(gA0, lA0); load_lds16(gA1, lA1);
        load_lds16(gB0, lB0); load_lds16(gB1, lB1);
        gA0 += 32; gA1 += 32; gB0 += 32; gB1 += 32;
        __syncthreads();   // drains vmcnt + barrier
        bf16x8 af[4], bfr[4];
#pragma unroll
        for (int i = 0; i < 4; ++i)
            af[i] = *(const bf16x8*)&As[(wm * 64 + i * 16 + l15) * 32 + quad * 8];
#pragma unroll
        for (int j = 0; j < 4; ++j)
            bfr[j] = *(const bf16x8*)&Bs[(wn * 64 + j * 16 + l15) * 32 + quad * 8];
#pragma unroll
        for (int i = 0; i < 4; ++i)
#pragma unroll
            for (int j = 0; j < 4; ++j)
                acc[i][j] = mfma16(af[i], bfr[j], acc[i][j]);
        __syncthreads();
    }

    const int r0 = quad * 4;
#pragma unroll
    for (int j = 0; j < 4; ++j) {
        int col = n0 + wn * 64 + j * 16 + l15;
        float bv = bias[col];
#pragma unroll
        for (int i = 0; i < 4; ++i) {
            int rowb = m0 + wm * 64 + i * 16 + r0;
#pragma unroll
            for (int r = 0; r < 4; ++r) {
                float v = acc[i][j][r] + bv;
                if (do_relu) v = fmaxf(v, 0.f);
                C[(size_t)(rowb + r) * N + col] = f2b(v);
            }
        }
    }
}

// ---------------------------------------------------------------------------
// ASYNC score GEMM: Sc[z][s][t] = mask(h[z][s]·h[z][t]), triangular block skip.
// grid (S/128, S/128, nb); x = m-tile, y = n-tile.
// ---------------------------------------------------------------------------
__global__ __launch_bounds__(256) void score_a(
    const u16* __restrict__ h, u16* __restrict__ Sc)
{
    __shared__ __attribute__((aligned(16))) u16 As[128 * 32];
    __shared__ __attribute__((aligned(16))) u16 Bs[128 * 32];

    const int m0 = blockIdx.x * 128;
    const int n0 = blockIdx.y * 128;
    if (n0 > m0 + 127) return;   // fully-masked block

    const u16* A = h  + (size_t)blockIdx.z * S_ * DH;
    u16*       C = Sc + (size_t)blockIdx.z * S_ * S_;

    const int tid  = threadIdx.x;
    const int lane = tid & 63;
    const int w    = tid >> 6;
    const int wm   = w >> 1, wn = w & 1;
    const int quad = lane >> 4, l15 = lane & 15;

    const int c0 = tid, c1 = tid + 256;
    const u16* gA0 = A + ((size_t)(m0 + (c0 >> 2)) * DH + (c0 & 3) * 8);
    const u16* gA1 = A + ((size_t)(m0 + (c1 >> 2)) * DH + (c1 & 3) * 8);
    const u16* gB0 = A + ((size_t)(n0 + (c0 >> 2)) * DH + (c0 & 3) * 8);
    const u16* gB1 = A + ((size_t)(n0 + (c1 >> 2)) * DH + (c1 & 3) * 8);
    u16* lA0 = &As[(w * 64) * 8];
    u16* lA1 = &As[(256 + w * 64) * 8];
    u16* lB0 = &Bs[(w * 64) * 8];
    u16* lB1 = &Bs[(256 + w * 64) * 8];

    f32x4 acc[4][4];
#pragma unroll
    for (int i = 0; i < 4; ++i)
#pragma unroll
        for (int j = 0; j < 4; ++j) acc[i][j] = (f32x4){0.f, 0.f, 0.f, 0.f};

    const int nk = DH >> 5;
    for (int kk = 0; kk < nk; ++kk) {
        load_lds16(gA0, lA0); load_lds16(gA1, lA1);
        load_lds16(gB0, lB0); load_lds16(gB1, lB1);
        gA0 += 32; gA1 += 32; gB0 += 32; gB1 += 32;
        __syncthreads();
        bf16x8 af[4], bfr[4];
#pragma unroll
        for (int i = 0; i < 4; ++i)
            af[i] = *(const bf16x8*)&As[(wm * 64 + i * 16 + l15) * 32 + quad * 8];
#pragma unroll
        for (int j = 0; j < 4; ++j)
            bfr[j] = *(const bf16x8*)&Bs[(wn * 64 + j * 16 + l15) * 32 + quad * 8];
#pragma unroll
        for (int i = 0; i < 4; ++i)
#pragma unroll
            for (int j = 0; j < 4; ++j)
                acc[i][j] = mfma16(af[i], bfr[j], acc[i][j]);
        __syncthreads();
    }

    const int r0 = quad * 4;
#pragma unroll
    for (int j = 0; j < 4; ++j) {
        int col = n0 + wn * 64 + j * 16 + l15;
#pragma unroll
        for (int i = 0; i < 4; ++i) {
            int rowb = m0 + wm * 64 + i * 16 + r0;
#pragma unroll
            for (int r = 0; r < 4; ++r) {
                int row = rowb + r;
                float v = (col <= row) ? acc[i][j][r] : MASKVAL;
                C[(size_t)row * S_ + col] = f2b(v);
            }
        }
    }
}

// ---------------------------------------------------------------------------
// ASYNC pv GEMM: ctx[z] = P[z] @ V[z]; A=P [S,S], Bt=hT [DH,S]. Causal k-limit.
// grid (S/128, DH/128, nb).
// ---------------------------------------------------------------------------
__global__ __launch_bounds__(256) void pv_a(
    const u16* __restrict__ P, const u16* __restrict__ hT, u16* __restrict__ ctx)
{
    __shared__ __attribute__((aligned(16))) u16 As[128 * 32];
    __shared__ __attribute__((aligned(16))) u16 Bs[128 * 32];

    const int m0 = blockIdx.x * 128;
    const int n0 = blockIdx.y * 128;
    const u16* A  = P   + (size_t)blockIdx.z * S_ * S_;
    const u16* Bt = hT  + (size_t)blockIdx.z * DH * S_;
    u16*       C  = ctx + (size_t)blockIdx.z * S_ * DH;

    const int tid  = threadIdx.x;
    const int lane = tid & 63;
    const int w    = tid >> 6;
    const int wm   = w >> 1, wn = w & 1;
    const int quad = lane >> 4, l15 = lane & 15;

    const int c0 = tid, c1 = tid + 256;
    const u16* gA0 = A  + ((size_t)(m0 + (c0 >> 2)) * S_ + (c0 & 3) * 8);
    const u16* gA1 = A  + ((size_t)(m0 + (c1 >> 2)) * S_ + (c1 & 3) * 8);
    const u16* gB0 = Bt + ((size_t)(n0 + (c0 >> 2)) * S_ + (c0 & 3) * 8);
    const u16* gB1 = Bt + ((size_t)(n0 + (c1 >> 2)) * S_ + (c1 & 3) * 8);
    u16* lA0 = &As[(w * 64) * 8];
    u16* lA1 = &As[(256 + w * 64) * 8];
    u16* lB0 = &Bs[(w * 64) * 8];
    u16* lB1 = &Bs[(256 + w * 64) * 8];

    f32x4 acc[4][4];
#pragma unroll
    for (int i = 0; i < 4; ++i)
#pragma unroll
        for (int j = 0; j < 4; ++j) acc[i][j] = (f32x4){0.f, 0.f, 0.f, 0.f};

    const int nk = (m0 + 128) >> 5;   // causal k-limit
    for (int kk = 0; kk < nk; ++kk) {
        load_lds16(gA0, lA0); load_lds16(gA1, lA1);
        load_lds16(gB0, lB0); load_lds16(gB1, lB1);
        gA0 += 32; gA1 += 32; gB0 += 32; gB1 += 32;
        __syncthreads();
        bf16x8 af[4], bfr[4];
#pragma unroll
        for (int i = 0; i < 4; ++i)
            af[i] = *(const bf16x8*)&As[(wm * 64 + i * 16 + l15) * 32 + quad * 8];
#pragma unroll
        for (int j = 0; j < 4; ++j)
            bfr[j] = *(const bf16x8*)&Bs[(wn * 64 + j * 16 + l15) * 32 + quad * 8];
#pragma unroll
        for (int i = 0; i < 4; ++i)
#pragma unroll
            for (int j = 0; j < 4; ++j)
                acc[i][j] = mfma16(af[i], bfr[j], acc[i][j]);
        __syncthreads();
    }

    const int r0 = quad * 4;
#pragma unroll
    for (int j = 0; j < 4; ++j) {
        int col = n0 + wn * 64 + j * 16 + l15;
#pragma unroll
        for (int i = 0; i < 4; ++i) {
            int rowb = m0 + wm * 64 + i * 16 + r0;
#pragma unroll
            for (int r = 0; r < 4; ++r)
                C[(size_t)(rowb + r) * DH + col] = f2b(acc[i][j][r]);
        }
    }
}

// ---------------------------------------------------------------------------
// SYNC-staged GEMM (tier-C fallback only; A may be f32)
// ---------------------------------------------------------------------------
template<bool AF32>
__global__ __launch_bounds__(256) void gemm_bt_bias_relu(
    const void* __restrict__ A, const u16* __restrict__ Bt,
    const float* __restrict__ bias, u16* __restrict__ C,
    int M, int N, int K, int do_relu)
{
    __shared__ __attribute__((aligned(16))) u16 As[128 * 32];
    __shared__ __attribute__((aligned(16))) u16 Bs[128 * 32];

    const int tid  = threadIdx.x;
    const int lane = tid & 63;
    const int w    = tid >> 6;
    const int wm   = w >> 1, wn = w & 1;
    const int quad = lane >> 4, l15 = lane & 15;

    const int m0 = blockIdx.x * 128;
    const int n0 = blockIdx.y * 128;

    const int c0 = tid, c1 = tid + 256;
    size_t eA0 = (size_t)(m0 + (c0 >> 2)) * K + (c0 & 3) * 8;
    size_t eA1 = (size_t)(m0 + (c1 >> 2)) * K + (c1 & 3) * 8;
    size_t eB0 = (size_t)(n0 + (c0 >> 2)) * K + (c0 & 3) * 8;
    size_t eB1 = (size_t)(n0 + (c1 >> 2)) * K + (c1 & 3) * 8;

    f32x4 acc[4][4];
#pragma unroll
    for (int i = 0; i < 4; ++i)
#pragma unroll
        for (int j = 0; j < 4; ++j) acc[i][j] = (f32x4){0.f, 0.f, 0.f, 0.f};

    uint4 va0 = ld8<AF32>(A, eA0), va1 = ld8<AF32>(A, eA1);
    uint4 vb0 = ld8<false>(Bt, eB0), vb1 = ld8<false>(Bt, eB1);

    const int nk = K >> 5;
    for (int kk = 0; kk < nk; ++kk) {
        __syncthreads();
        *(uint4*)&As[c0 * 8] = va0;
        *(uint4*)&As[c1 * 8] = va1;
        *(uint4*)&Bs[c0 * 8] = vb0;
        *(uint4*)&Bs[c1 * 8] = vb1;
        if (kk + 1 < nk) {
            eA0 += 32; eA1 += 32; eB0 += 32; eB1 += 32;
            va0 = ld8<AF32>(A, eA0); va1 = ld8<AF32>(A, eA1);
            vb0 = ld8<false>(Bt, eB0); vb1 = ld8<false>(Bt, eB1);
        }
        __syncthreads();
        bf16x8 af[4], bfr[4];
#pragma unroll
        for (int i = 0; i < 4; ++i)
            af[i] = *(const bf16x8*)&As[(wm * 64 + i * 16 + l15) * 32 + quad * 8];
#pragma unroll
        for (int j = 0; j < 4; ++j)
            bfr[j] = *(const bf16x8*)&Bs[(wn * 64 + j * 16 + l15) * 32 + quad * 8];
#pragma unroll
        for (int i = 0; i < 4; ++i)
#pragma unroll
            for (int j = 0; j < 4; ++j)
                acc[i][j] = mfma16(af[i], bfr[j], acc[i][j]);
    }

    const int r0 = quad * 4;
#pragma unroll
    for (int j = 0; j < 4; ++j) {
        int col = n0 + wn * 64 + j * 16 + l15;
        float bv = bias[col];
#pragma unroll
        for (int i = 0; i < 4; ++i) {
            int rowb = m0 + wm * 64 + i * 16 + r0;
#pragma unroll
            for (int r = 0; r < 4; ++r) {
                float v = acc[i][j][r] + bv;
                if (do_relu) v = fmaxf(v, 0.f);
                C[(size_t)(rowb + r) * N + col] = f2b(v);
            }
        }
    }
}

// ---------------------------------------------------------------------------
// softmax_rows: in-place causal-limited row softmax of Sc (bf16).
// One wave per row; reads/writes only kb*512 cols (covers pv's k-limit).
// ---------------------------------------------------------------------------
__global__ __launch_bounds__(256) void softmax_rows(u16* __restrict__ Sc)
{
    const int tid = threadIdx.x;
    const int lane = tid & 63, w = tid >> 6;
    const size_t row = (size_t)blockIdx.x * 4 + w;
    const int rloc = (int)(row & (S_ - 1));
    const int kb = ((rloc >> 7) + 4) >> 2;   // 1..4 blocks of 512 cols
    u16* p = Sc + row * S_;
    float v[32];
    float m = -1e30f;
    for (int k = 0; k < kb; ++k) {
        uint4 u = *(const uint4*)&p[k * 512 + lane * 8];
        const u32* uu = (const u32*)&u;
#pragma unroll
        for (int i = 0; i < 4; ++i) {
            float a = b2f((u16)(uu[i] & 0xFFFFu));
            float b = b2f((u16)(uu[i] >> 16));
            v[k * 8 + 2 * i] = a; v[k * 8 + 2 * i + 1] = b;
            m = fmaxf(m, fmaxf(a, b));
        }
    }
#pragma unroll
    for (int off = 32; off >= 1; off >>= 1) m = fmaxf(m, __shfl_xor(m, off, 64));
    float s = 0.f;
    for (int k = 0; k < kb; ++k)
#pragma unroll
        for (int i = 0; i < 8; ++i) {
            float e = __expf(v[k * 8 + i] - m);
            v[k * 8 + i] = e; s += e;
        }
#pragma unroll
    for (int off = 32; off >= 1; off >>= 1) s += __shfl_xor(s, off, 64);
    float inv = 1.0f / s;
    for (int k = 0; k < kb; ++k) {
        uint4 u; u32* uu = (u32*)&u;
#pragma unroll
        for (int i = 0; i < 4; ++i)
            uu[i] = pack2(v[k * 8 + 2 * i] * inv, v[k * 8 + 2 * i + 1] * inv);
        *(uint4*)&p[k * 512 + lane * 8] = u;
    }
}

// ---------------------------------------------------------------------------
// transpose + f32->bf16 convert: in f32 [R][C] -> out bf16 [C][R]. block (32,8)
// ---------------------------------------------------------------------------
__global__ __launch_bounds__(256) void transpose_cvt(
    const float* __restrict__ in, u16* __restrict__ out, int R, int C)
{
    __shared__ u16 t[32][33];
    int c0 = blockIdx.x * 32, r0 = blockIdx.y * 32;
    int tx = threadIdx.x, ty = threadIdx.y;
#pragma unroll
    for (int i = 0; i < 4; ++i)
        t[ty + i * 8][tx] = f2b(in[(size_t)(r0 + ty + i * 8) * C + c0 + tx]);
    __syncthreads();
#pragma unroll
    for (int i = 0; i < 4; ++i)
        out[(size_t)(c0 + ty + i * 8) * R + r0 + tx] = t[tx][ty + i * 8];
}

// batched bf16 transpose: in [z][R][C] -> out [z][C][R]. block (32,8)
__global__ __launch_bounds__(256) void transpose_b(
    const u16* __restrict__ in, u16* __restrict__ out, int R, int C)
{
    __shared__ u16 t[32][33];
    const u16* ip = in  + (size_t)blockIdx.z * R * C;
    u16*       op = out + (size_t)blockIdx.z * R * C;
    int c0 = blockIdx.x * 32, r0 = blockIdx.y * 32;
    int tx = threadIdx.x, ty = threadIdx.y;
#pragma unroll
    for (int i = 0; i < 4; ++i)
        t[ty + i * 8][tx] = ip[(size_t)(r0 + ty + i * 8) * C + c0 + tx];
    __syncthreads();
#pragma unroll
    for (int i = 0; i < 4; ++i)
        op[(size_t)(c0 + ty + i * 8) * R + r0 + tx] = t[tx][ty + i * 8];
}

// ---------------------------------------------------------------------------
// head: out[row,:] = log_softmax(o[row,:] @ W4 + b4). One wave per row.
// ---------------------------------------------------------------------------
__global__ __launch_bounds__(256) void head_logsoftmax(
    const u16* __restrict__ o, const float* __restrict__ W4,
    const float* __restrict__ b4, float* __restrict__ out)
{
    __shared__ float W4s[DIN * DOUT];
    __shared__ float b4s[DOUT];
    const int tid = threadIdx.x;
    for (int i = tid; i < DIN * DOUT; i += 256) W4s[i] = W4[i];
    if (tid < DOUT) b4s[tid] = b4[tid];
    __syncthreads();
    const int lane = tid & 63, w = tid >> 6;
    const size_t row = (size_t)blockIdx.x * 4 + w;
    const uint4 ov = *(const uint4*)&o[row * DIN + lane * 8];
    const u32* ou = (const u32*)&ov;
    float oc[8];
#pragma unroll
    for (int i = 0; i < 4; ++i) {
        oc[2*i]   = b2f((u16)(ou[i] & 0xFFFFu));
        oc[2*i+1] = b2f((u16)(ou[i] >> 16));
    }
    float acc[DOUT];
#pragma unroll
    for (int c = 0; c < DOUT; ++c) acc[c] = 0.f;
#pragma unroll
    for (int i = 0; i < 8; ++i) {
        int k = lane * 8 + i;
        float x = oc[i];
#pragma unroll
        for (int c = 0; c < DOUT; ++c) acc[c] += x * W4s[k * DOUT + c];
    }
#pragma unroll
    for (int off = 32; off >= 1; off >>= 1)
#pragma unroll
        for (int c = 0; c < DOUT; ++c) acc[c] += __shfl_xor(acc[c], off, 64);
    float mx = -1e30f;
#pragma unroll
    for (int c = 0; c < DOUT; ++c) { acc[c] += b4s[c]; mx = fmaxf(mx, acc[c]); }
    float sum = 0.f;
#pragma unroll
    for (int c = 0; c < DOUT; ++c) sum += __expf(acc[c] - mx);
    float lse = mx + logf(sum);
    if (lane == 0) {
#pragma unroll
        for (int c = 0; c < DOUT; ++c) out[row * DOUT + c] = acc[c] - lse;
    }
}

// ---------------------------------------------------------------------------
extern "C" void kernel_launch(void* const* d_in, const int* in_sizes, int n_in,
                              void* d_out, int out_size, void* d_ws, size_t ws_size,
                              hipStream_t stream) {
    const float* x  = (const float*)d_in[0];
    const float* gv = (const float*)d_in[1];
    const float* uv = (const float*)d_in[2];
    const float* W1 = (const float*)d_in[3];
    const float* b1 = (const float*)d_in[4];
    const float* W2 = (const float*)d_in[5];
    const float* b2 = (const float*)d_in[6];
    const float* W3 = (const float*)d_in[7];
    const float* b3 = (const float*)d_in[8];
    const float* W4 = (const float*)d_in[9];
    const float* b4 = (const float*)d_in[10];
    float* out = (float*)d_out;

    char* ws = (char*)d_ws;
    const size_t MB64 = (size_t)67108864;
    const size_t MiB  = (size_t)1048576;
    const size_t TIER_A = 2 * MB64 + 160 * MiB + 4 * MiB;   // 292 MiB
    const size_t TIER_B = 3 * MB64 + 5 * MiB;               // 197 MiB (proven)

    if (ws_size >= TIER_A) {
        // R0 h1/ctx 64Mi | R1 h 64Mi | R2 {xb -> hT 32Mi + P 128Mi -> o} | weights
        u16* h1  = (u16*)(ws);
        u16* ctx = h1;
        u16* h   = (u16*)(ws + MB64);
        u16* xb  = (u16*)(ws + 2 * MB64);              // 32 Mi (dead after GEMM1)
        u16* hT  = (u16*)(ws + 2 * MB64);              // 32 Mi
        u16* P   = (u16*)(ws + 2 * MB64 + 32 * MiB);   // 128 Mi
        u16* o   = (u16*)(ws + 2 * MB64);              // 32 Mi (after attention)
        u16* W1t = (u16*)(ws + 2 * MB64 + 160 * MiB);
        u16* W2t = W1t + 512 * 1024;
        u16* W3t = W2t + 1024 * 1024;

        cvt_f32_bf16<<<8192, 256, 0, stream>>>(x, xb, 2097152);
        transpose_cvt<<<dim3(32, 16), dim3(32, 8), 0, stream>>>(W1, W1t, 512, 1024);
        transpose_cvt<<<dim3(32, 32), dim3(32, 8), 0, stream>>>(W2, W2t, 1024, 1024);
        transpose_cvt<<<dim3(16, 32), dim3(32, 8), 0, stream>>>(W3, W3t, 1024, 512);

        gemm_a<<<dim3(8, 256), 256, 0, stream>>>(xb, W1t, b1, h1, 32768, 1024, 512, 1);
        gemm_a<<<dim3(8, 256), 256, 0, stream>>>(h1, W2t, b2, h,  32768, 1024, 1024, 1);

        transpose_b<<<dim3(32, 64, 16), dim3(32, 8), 0, stream>>>(h, hT, 2048, 1024);
        score_a<<<dim3(16, 16, 16), 256, 0, stream>>>(h, P);
        softmax_rows<<<8192, 256, 0, stream>>>(P);
        pv_a<<<dim3(16, 8, 16), 256, 0, stream>>>(P, hT, ctx);

        gemm_a<<<dim3(4, 256), 256, 0, stream>>>(ctx, W3t, b3, o, 32768, 512, 1024, 1);
        head_logsoftmax<<<8192, 256, 0, stream>>>(o, W4, b4, out);
    } else if (ws_size >= TIER_B) {
        // R0 h1/ctx | R1 h | R2 {xb 32Mi -> hT_c 16Mi + P_c 34Mi -> o 32Mi} | weights
        u16* h1   = (u16*)(ws);
        u16* ctx  = h1;
        u16* h    = (u16*)(ws + MB64);
        u16* xb   = (u16*)(ws + 2 * MB64);
        u16* hT_c = (u16*)(ws + 2 * MB64);
        u16* P_c  = (u16*)(ws + 2 * MB64 + 16 * MiB);
        u16* o    = (u16*)(ws + 2 * MB64);
        u16* W1t  = (u16*)(ws + 3 * MB64);
        u16* W2t  = W1t + 512 * 1024;
        u16* W3t  = W2t + 1024 * 1024;

        cvt_f32_bf16<<<8192, 256, 0, stream>>>(x, xb, 2097152);
        transpose_cvt<<<dim3(32, 16), dim3(32, 8), 0, stream>>>(W1, W1t, 512, 1024);
        transpose_cvt<<<dim3(32, 32), dim3(32, 8), 0, stream>>>(W2, W2t, 1024, 1024);
        transpose_cvt<<<dim3(16, 32), dim3(32, 8), 0, stream>>>(W3, W3t, 1024, 512);

        gemm_a<<<dim3(8, 256), 256, 0, stream>>>(xb, W1t, b1, h1, 32768, 1024, 512, 1);
        gemm_a<<<dim3(8, 256), 256, 0, stream>>>(h1, W2t, b2, h,  32768, 1024, 1024, 1);

        for (int c = 0; c < 4; ++c) {
            const u16* hc  = h   + (size_t)c * 4 * S_ * DH;
            u16*       cxc = ctx + (size_t)c * 4 * S_ * DH;
            transpose_b<<<dim3(32, 64, 4), dim3(32, 8), 0, stream>>>(hc, hT_c, 2048, 1024);
            score_a<<<dim3(16, 16, 4), 256, 0, stream>>>(hc, P_c);
            softmax_rows<<<2048, 256, 0, stream>>>(P_c);
            pv_a<<<dim3(16, 8, 4), 256, 0, stream>>>(P_c, hT_c, cxc);
        }

        gemm_a<<<dim3(4, 256), 256, 0, stream>>>(ctx, W3t, b3, o, 32768, 512, 1024, 1);
        head_logsoftmax<<<8192, 256, 0, stream>>>(o, W4, b4, out);
    } else {
        // Compact fallback (~86 MiB): per-batch attention through small scratch
        u16* h    = (u16*)(ws);                          // 64 Mi
        u16* hT_b = (u16*)(ws + MB64);                   // 4 Mi
        u16* P_b  = (u16*)(ws + MB64 + 4 * MiB);         // 8 Mi
        u16* ctx_b= (u16*)(ws + MB64 + 12 * MiB);        // 4 Mi
        u16* o_b  = (u16*)(ws + MB64 + 16 * MiB);        // 2 Mi
        u16* W1t  = (u16*)(ws + MB64 + 18 * MiB);
        u16* W2t  = W1t + 512 * 1024;
        u16* W3t  = W2t + 1024 * 1024;
        u16* h1_b = P_b;

        transpose_cvt<<<dim3(32, 16), dim3(32, 8), 0, stream>>>(W1, W1t, 512, 1024);
        transpose_cvt<<<dim3(32, 32), dim3(32, 8), 0, stream>>>(W2, W2t, 1024, 1024);
        transpose_cvt<<<dim3(16, 32), dim3(32, 8), 0, stream>>>(W3, W3t, 1024, 512);

        for (int c = 0; c < 8; ++c) {
            const float* xc = x + (size_t)c * 4096 * DIN;
            u16*         hc = h + (size_t)c * 4096 * DH;
            gemm_bt_bias_relu<true ><<<dim3(32, 8), 256, 0, stream>>>(xc, W1t, b1, h1_b,
                                                                      4096, 1024, 512, 1);
            gemm_bt_bias_relu<false><<<dim3(32, 8), 256, 0, stream>>>(h1_b, W2t, b2, hc,
                                                                      4096, 1024, 1024, 1);
        }
        for (int b = 0; b < B_; ++b) {
            const u16* hb = h + (size_t)b * S_ * DH;
            transpose_b<<<dim3(32, 64, 1), dim3(32, 8), 0, stream>>>(hb, hT_b, 2048, 1024);
            score_a<<<dim3(16, 16, 1), 256, 0, stream>>>(hb, P_b);
            softmax_rows<<<512, 256, 0, stream>>>(P_b);
            pv_a<<<dim3(16, 8, 1), 256, 0, stream>>>(P_b, hT_b, ctx_b);
            gemm_bt_bias_relu<false><<<dim3(16, 4), 256, 0, stream>>>(ctx_b, W3t, b3, o_b,
                                                                      2048, 512, 1024, 1);
            head_logsoftmax<<<512, 256, 0, stream>>>(o_b, W4, b4,
                                                     out + (size_t)b * S_ * DOUT);
        }
    }

    // pass-throughs (f32)
    size_t n_gv = (size_t)in_sizes[1], n_uv = (size_t)in_sizes[2];
    size_t o0 = (size_t)out_size - n_gv - n_uv;
    hipMemcpyAsync(out + o0,        gv, n_gv * 4, hipMemcpyDeviceToDevice, stream);
    hipMemcpyAsync(out + o0 + n_gv, uv, n_uv * 4, hipMemcpyDeviceToDevice, stream);
}

// Round 9
// 821.168 us; speedup vs baseline: 1.0611x; 1.0611x over previous
//
#include <hip/hip_runtime.h>
#include <stdint.h>

// Problem constants (fixed by reference)
#define B_   16
#define S_   2048
#define DIN  512
#define DH   1024
#define DOUT 10

typedef unsigned short u16;
typedef unsigned int   u32;

typedef __bf16 bf16_t;
typedef bf16_t bf16x8 __attribute__((ext_vector_type(8)));
typedef float  f32x4  __attribute__((ext_vector_type(4)));

#define MASKVAL (-3.0e4f)
// Packed-P geometry: row-block mi holds r4 = ((mi>>2)+1)*4 tiles of 128 cols.
// Tile-offset of row-block mi: S4(mi) = 4*(g+1)*(mi-2g), g = mi>>2.
// Per-batch packed size = 160 tiles * 16384 u16 = 5 MiB.
#define PZ_U16 ((size_t)160 * 16384)

__device__ __forceinline__ float b2f(u16 u) {
    union { u32 i; float f; } v; v.i = ((u32)u) << 16; return v.f;
}
__device__ __forceinline__ u16 f2b(float f) {
    union { float f; u32 i; } v; v.f = f;
    u32 u = v.i;
    u32 r = (u + 0x7FFFu + ((u >> 16) & 1u)) >> 16;  // RNE
    return (u16)r;
}
__device__ __forceinline__ u32 pack2(float a, float b) {
    return (u32)f2b(a) | ((u32)f2b(b) << 16);
}

__device__ __forceinline__ f32x4 mfma16(bf16x8 a, bf16x8 b, f32x4 c) {
    return __builtin_amdgcn_mfma_f32_16x16x32_bf16(a, b, c, 0, 0, 0);
}

// async global->LDS, 16B per lane; LDS dest = wave-uniform base + lane*16
__device__ __forceinline__ void load_lds16(const u16* g, u16* l) {
    __builtin_amdgcn_global_load_lds(
        (__attribute__((address_space(1))) u32*)(g),
        (__attribute__((address_space(3))) u32*)(l), 16, 0, 0);
}

// load 8 contiguous elements at element-index eidx as packed bf16x8 (uint4)
template<bool F32>
__device__ __forceinline__ uint4 ld8(const void* base, size_t eidx) {
    if constexpr (F32) {
        const float* p = (const float*)base + eidx;
        float4 f0 = *(const float4*)p;
        float4 f1 = *(const float4*)(p + 4);
        uint4 r;
        r.x = pack2(f0.x, f0.y); r.y = pack2(f0.z, f0.w);
        r.z = pack2(f1.x, f1.y); r.w = pack2(f1.z, f1.w);
        return r;
    } else {
        return *(const uint4*)((const u16*)base + eidx);
    }
}

// ---------------------------------------------------------------------------
// f32 -> bf16 elementwise convert (8 elems/thread)
// ---------------------------------------------------------------------------
__global__ __launch_bounds__(256) void cvt_f32_bf16(
    const float* __restrict__ in, u16* __restrict__ out, int n8)
{
    int i = blockIdx.x * 256 + threadIdx.x;
    if (i >= n8) return;
    size_t e = (size_t)i * 8;
    float4 f0 = *(const float4*)(in + e);
    float4 f1 = *(const float4*)(in + e + 4);
    uint4 r;
    r.x = pack2(f0.x, f0.y); r.y = pack2(f0.z, f0.w);
    r.z = pack2(f1.x, f1.y); r.w = pack2(f1.z, f1.w);
    *(uint4*)(out + e) = r;
}

// ---------------------------------------------------------------------------
// ASYNC-staged GEMM: C[M,N] = relu(A[M,K] @ Bt[N,K]^T + bias[N]), all bf16.
// grid x = M/128 (m-fast, round-6 proven), y = N/128.
// ---------------------------------------------------------------------------
__global__ __launch_bounds__(256) void gemm_a(
    const u16* __restrict__ A, const u16* __restrict__ Bt,
    const float* __restrict__ bias, u16* __restrict__ C,
    int M, int N, int K, int do_relu)
{
    __shared__ __attribute__((aligned(16))) u16 As[128 * 32];
    __shared__ __attribute__((aligned(16))) u16 Bs[128 * 32];

    const int tid  = threadIdx.x;
    const int lane = tid & 63;
    const int w    = tid >> 6;
    const int wm   = w >> 1, wn = w & 1;
    const int quad = lane >> 4, l15 = lane & 15;

    const int m0 = blockIdx.x * 128;
    const int n0 = blockIdx.y * 128;

    const int c0 = tid, c1 = tid + 256;
    const u16* gA0 = A  + ((size_t)(m0 + (c0 >> 2)) * K + (c0 & 3) * 8);
    const u16* gA1 = A  + ((size_t)(m0 + (c1 >> 2)) * K + (c1 & 3) * 8);
    const u16* gB0 = Bt + ((size_t)(n0 + (c0 >> 2)) * K + (c0 & 3) * 8);
    const u16* gB1 = Bt + ((size_t)(n0 + (c1 >> 2)) * K + (c1 & 3) * 8);
    u16* lA0 = &As[(w * 64) * 8];
    u16* lA1 = &As[(256 + w * 64) * 8];
    u16* lB0 = &Bs[(w * 64) * 8];
    u16* lB1 = &Bs[(256 + w * 64) * 8];

    f32x4 acc[4][4];
#pragma unroll
    for (int i = 0; i < 4; ++i)
#pragma unroll
        for (int j = 0; j < 4; ++j) acc[i][j] = (f32x4){0.f, 0.f, 0.f, 0.f};

    const int nk = K >> 5;
    for (int kk = 0; kk < nk; ++kk) {
        load_lds16(gA0, lA0); load_lds16(gA1, lA1);
        load_lds16(gB0, lB0); load_lds16(gB1, lB1);
        gA0 += 32; gA1 += 32; gB0 += 32; gB1 += 32;
        __syncthreads();
        bf16x8 af[4], bfr[4];
#pragma unroll
        for (int i = 0; i < 4; ++i)
            af[i] = *(const bf16x8*)&As[(wm * 64 + i * 16 + l15) * 32 + quad * 8];
#pragma unroll
        for (int j = 0; j < 4; ++j)
            bfr[j] = *(const bf16x8*)&Bs[(wn * 64 + j * 16 + l15) * 32 + quad * 8];
#pragma unroll
        for (int i = 0; i < 4; ++i)
#pragma unroll
            for (int j = 0; j < 4; ++j)
                acc[i][j] = mfma16(af[i], bfr[j], acc[i][j]);
        __syncthreads();
    }

    const int r0 = quad * 4;
#pragma unroll
    for (int j = 0; j < 4; ++j) {
        int col = n0 + wn * 64 + j * 16 + l15;
        float bv = bias[col];
#pragma unroll
        for (int i = 0; i < 4; ++i) {
            int rowb = m0 + wm * 64 + i * 16 + r0;
#pragma unroll
            for (int r = 0; r < 4; ++r) {
                float v = acc[i][j][r] + bv;
                if (do_relu) v = fmaxf(v, 0.f);
                C[(size_t)(rowb + r) * N + col] = f2b(v);
            }
        }
    }
}

// ---------------------------------------------------------------------------
// ASYNC score GEMM into PACKED P: row-block mi = causal tiles ni<=mi,
// padded to r4 tiles; pad tiles get MASKVAL. grid (16, 16, nb).
// ---------------------------------------------------------------------------
__global__ __launch_bounds__(256) void score_a(
    const u16* __restrict__ h, u16* __restrict__ P)
{
    __shared__ __attribute__((aligned(16))) u16 As[128 * 32];
    __shared__ __attribute__((aligned(16))) u16 Bs[128 * 32];

    const int mi = blockIdx.x, ni = blockIdx.y;
    const int g  = mi >> 2;
    const int r4 = (g + 1) * 4;
    if (ni >= r4) return;

    const int tid = threadIdx.x;
    u16* Pz = P + (size_t)blockIdx.z * PZ_U16
                + (size_t)(4 * (g + 1) * (mi - 2 * g)) * 16384;
    const size_t rstride = (size_t)r4 * 128;

    if (ni > mi) {                               // pad tile: MASKVAL fill
        const u16 mb = f2b(MASKVAL);
        const u32 m2 = (u32)mb | ((u32)mb << 16);
        uint4 mv; mv.x = m2; mv.y = m2; mv.z = m2; mv.w = m2;
#pragma unroll
        for (int i = 0; i < 8; ++i) {
            int q = tid + i * 256;
            int row = q >> 4, cl = (q & 15) * 8;
            *(uint4*)&Pz[(size_t)row * rstride + ni * 128 + cl] = mv;
        }
        return;
    }

    const int m0 = mi * 128, n0 = ni * 128;
    const u16* A = h + (size_t)blockIdx.z * S_ * DH;

    const int lane = tid & 63;
    const int w    = tid >> 6;
    const int wm   = w >> 1, wn = w & 1;
    const int quad = lane >> 4, l15 = lane & 15;

    const int c0 = tid, c1 = tid + 256;
    const u16* gA0 = A + ((size_t)(m0 + (c0 >> 2)) * DH + (c0 & 3) * 8);
    const u16* gA1 = A + ((size_t)(m0 + (c1 >> 2)) * DH + (c1 & 3) * 8);
    const u16* gB0 = A + ((size_t)(n0 + (c0 >> 2)) * DH + (c0 & 3) * 8);
    const u16* gB1 = A + ((size_t)(n0 + (c1 >> 2)) * DH + (c1 & 3) * 8);
    u16* lA0 = &As[(w * 64) * 8];
    u16* lA1 = &As[(256 + w * 64) * 8];
    u16* lB0 = &Bs[(w * 64) * 8];
    u16* lB1 = &Bs[(256 + w * 64) * 8];

    f32x4 acc[4][4];
#pragma unroll
    for (int i = 0; i < 4; ++i)
#pragma unroll
        for (int j = 0; j < 4; ++j) acc[i][j] = (f32x4){0.f, 0.f, 0.f, 0.f};

    const int nk = DH >> 5;
    for (int kk = 0; kk < nk; ++kk) {
        load_lds16(gA0, lA0); load_lds16(gA1, lA1);
        load_lds16(gB0, lB0); load_lds16(gB1, lB1);
        gA0 += 32; gA1 += 32; gB0 += 32; gB1 += 32;
        __syncthreads();
        bf16x8 af[4], bfr[4];
#pragma unroll
        for (int i = 0; i < 4; ++i)
            af[i] = *(const bf16x8*)&As[(wm * 64 + i * 16 + l15) * 32 + quad * 8];
#pragma unroll
        for (int j = 0; j < 4; ++j)
            bfr[j] = *(const bf16x8*)&Bs[(wn * 64 + j * 16 + l15) * 32 + quad * 8];
#pragma unroll
        for (int i = 0; i < 4; ++i)
#pragma unroll
            for (int j = 0; j < 4; ++j)
                acc[i][j] = mfma16(af[i], bfr[j], acc[i][j]);
        __syncthreads();
    }

    const int r0 = quad * 4;
#pragma unroll
    for (int j = 0; j < 4; ++j) {
        int cl = wn * 64 + j * 16 + l15;
#pragma unroll
        for (int i = 0; i < 4; ++i) {
            int rl = wm * 64 + i * 16 + r0;
#pragma unroll
            for (int r = 0; r < 4; ++r) {
                int row = rl + r;
                float v = (n0 + cl <= m0 + row) ? acc[i][j][r] : MASKVAL;
                Pz[(size_t)row * rstride + ni * 128 + cl] = f2b(v);
            }
        }
    }
}

// ---------------------------------------------------------------------------
// softmax_rows: in-place row softmax of packed P. One wave per row.
// Row length = kb*512 cols (kb = (mi>>2)+1), includes MASKVAL padding.
// ---------------------------------------------------------------------------
__global__ __launch_bounds__(256) void softmax_rows(u16* __restrict__ P)
{
    const int tid = threadIdx.x;
    const int lane = tid & 63, w = tid >> 6;
    const size_t row = (size_t)blockIdx.x * 4 + w;
    const int z    = (int)(row >> 11);
    const int rloc = (int)(row & (S_ - 1));
    const int mi = rloc >> 7, g = mi >> 2;
    const int kb = g + 1;
    u16* p = P + (size_t)z * PZ_U16
               + (size_t)(4 * (g + 1) * (mi - 2 * g)) * 16384
               + (size_t)(rloc & 127) * ((g + 1) * 4 * 128);
    float v[32];
    float m = -1e30f;
    for (int k = 0; k < kb; ++k) {
        uint4 u = *(const uint4*)&p[k * 512 + lane * 8];
        const u32* uu = (const u32*)&u;
#pragma unroll
        for (int i = 0; i < 4; ++i) {
            float a = b2f((u16)(uu[i] & 0xFFFFu));
            float b = b2f((u16)(uu[i] >> 16));
            v[k * 8 + 2 * i] = a; v[k * 8 + 2 * i + 1] = b;
            m = fmaxf(m, fmaxf(a, b));
        }
    }
#pragma unroll
    for (int off = 32; off >= 1; off >>= 1) m = fmaxf(m, __shfl_xor(m, off, 64));
    float s = 0.f;
    for (int k = 0; k < kb; ++k)
#pragma unroll
        for (int i = 0; i < 8; ++i) {
            float e = __expf(v[k * 8 + i] - m);
            v[k * 8 + i] = e; s += e;
        }
#pragma unroll
    for (int off = 32; off >= 1; off >>= 1) s += __shfl_xor(s, off, 64);
    float inv = 1.0f / s;
    for (int k = 0; k < kb; ++k) {
        uint4 u; u32* uu = (u32*)&u;
#pragma unroll
        for (int i = 0; i < 4; ++i)
            uu[i] = pack2(v[k * 8 + 2 * i] * inv, v[k * 8 + 2 * i + 1] * inv);
        *(uint4*)&p[k * 512 + lane * 8] = u;
    }
}

// ---------------------------------------------------------------------------
// ASYNC pv GEMM: ctx[z] = P[z] @ V[z]; A = packed P, Bt = hT [DH,S].
// nk = (mi+1)*4 (real causal cols only). grid (16, 8, nb).
// ---------------------------------------------------------------------------
__global__ __launch_bounds__(256) void pv_a(
    const u16* __restrict__ P, const u16* __restrict__ hT, u16* __restrict__ ctx)
{
    __shared__ __attribute__((aligned(16))) u16 As[128 * 32];
    __shared__ __attribute__((aligned(16))) u16 Bs[128 * 32];

    const int mi = blockIdx.x, g = mi >> 2;
    const int m0 = mi * 128;
    const int n0 = blockIdx.y * 128;
    const size_t rstride = (size_t)((g + 1) * 4) * 128;
    const u16* A  = P  + (size_t)blockIdx.z * PZ_U16
                       + (size_t)(4 * (g + 1) * (mi - 2 * g)) * 16384;
    const u16* Bt = hT + (size_t)blockIdx.z * DH * S_;
    u16*      C   = ctx + (size_t)blockIdx.z * S_ * DH;

    const int tid  = threadIdx.x;
    const int lane = tid & 63;
    const int w    = tid >> 6;
    const int wm   = w >> 1, wn = w & 1;
    const int quad = lane >> 4, l15 = lane & 15;

    const int c0 = tid, c1 = tid + 256;
    const u16* gA0 = A  + ((size_t)(c0 >> 2) * rstride + (c0 & 3) * 8);
    const u16* gA1 = A  + ((size_t)(c1 >> 2) * rstride + (c1 & 3) * 8);
    const u16* gB0 = Bt + ((size_t)(n0 + (c0 >> 2)) * S_ + (c0 & 3) * 8);
    const u16* gB1 = Bt + ((size_t)(n0 + (c1 >> 2)) * S_ + (c1 & 3) * 8);
    u16* lA0 = &As[(w * 64) * 8];
    u16* lA1 = &As[(256 + w * 64) * 8];
    u16* lB0 = &Bs[(w * 64) * 8];
    u16* lB1 = &Bs[(256 + w * 64) * 8];

    f32x4 acc[4][4];
#pragma unroll
    for (int i = 0; i < 4; ++i)
#pragma unroll
        for (int j = 0; j < 4; ++j) acc[i][j] = (f32x4){0.f, 0.f, 0.f, 0.f};

    const int nk = (mi + 1) * 4;
    for (int kk = 0; kk < nk; ++kk) {
        load_lds16(gA0, lA0); load_lds16(gA1, lA1);
        load_lds16(gB0, lB0); load_lds16(gB1, lB1);
        gA0 += 32; gA1 += 32; gB0 += 32; gB1 += 32;
        __syncthreads();
        bf16x8 af[4], bfr[4];
#pragma unroll
        for (int i = 0; i < 4; ++i)
            af[i] = *(const bf16x8*)&As[(wm * 64 + i * 16 + l15) * 32 + quad * 8];
#pragma unroll
        for (int j = 0; j < 4; ++j)
            bfr[j] = *(const bf16x8*)&Bs[(wn * 64 + j * 16 + l15) * 32 + quad * 8];
#pragma unroll
        for (int i = 0; i < 4; ++i)
#pragma unroll
            for (int j = 0; j < 4; ++j)
                acc[i][j] = mfma16(af[i], bfr[j], acc[i][j]);
        __syncthreads();
    }

    const int r0 = quad * 4;
#pragma unroll
    for (int j = 0; j < 4; ++j) {
        int col = n0 + wn * 64 + j * 16 + l15;
#pragma unroll
        for (int i = 0; i < 4; ++i) {
            int rowb = m0 + wm * 64 + i * 16 + r0;
#pragma unroll
            for (int r = 0; r < 4; ++r)
                C[(size_t)(rowb + r) * DH + col] = f2b(acc[i][j][r]);
        }
    }
}

// ---------------------------------------------------------------------------
// SYNC-staged GEMM (tier-C fallback only; A may be f32)
// ---------------------------------------------------------------------------
template<bool AF32>
__global__ __launch_bounds__(256) void gemm_bt_bias_relu(
    const void* __restrict__ A, const u16* __restrict__ Bt,
    const float* __restrict__ bias, u16* __restrict__ C,
    int M, int N, int K, int do_relu)
{
    __shared__ __attribute__((aligned(16))) u16 As[128 * 32];
    __shared__ __attribute__((aligned(16))) u16 Bs[128 * 32];

    const int tid  = threadIdx.x;
    const int lane = tid & 63;
    const int w    = tid >> 6;
    const int wm   = w >> 1, wn = w & 1;
    const int quad = lane >> 4, l15 = lane & 15;

    const int m0 = blockIdx.x * 128;
    const int n0 = blockIdx.y * 128;

    const int c0 = tid, c1 = tid + 256;
    size_t eA0 = (size_t)(m0 + (c0 >> 2)) * K + (c0 & 3) * 8;
    size_t eA1 = (size_t)(m0 + (c1 >> 2)) * K + (c1 & 3) * 8;
    size_t eB0 = (size_t)(n0 + (c0 >> 2)) * K + (c0 & 3) * 8;
    size_t eB1 = (size_t)(n0 + (c1 >> 2)) * K + (c1 & 3) * 8;

    f32x4 acc[4][4];
#pragma unroll
    for (int i = 0; i < 4; ++i)
#pragma unroll
        for (int j = 0; j < 4; ++j) acc[i][j] = (f32x4){0.f, 0.f, 0.f, 0.f};

    uint4 va0 = ld8<AF32>(A, eA0), va1 = ld8<AF32>(A, eA1);
    uint4 vb0 = ld8<false>(Bt, eB0), vb1 = ld8<false>(Bt, eB1);

    const int nk = K >> 5;
    for (int kk = 0; kk < nk; ++kk) {
        __syncthreads();
        *(uint4*)&As[c0 * 8] = va0;
        *(uint4*)&As[c1 * 8] = va1;
        *(uint4*)&Bs[c0 * 8] = vb0;
        *(uint4*)&Bs[c1 * 8] = vb1;
        if (kk + 1 < nk) {
            eA0 += 32; eA1 += 32; eB0 += 32; eB1 += 32;
            va0 = ld8<AF32>(A, eA0); va1 = ld8<AF32>(A, eA1);
            vb0 = ld8<false>(Bt, eB0); vb1 = ld8<false>(Bt, eB1);
        }
        __syncthreads();
        bf16x8 af[4], bfr[4];
#pragma unroll
        for (int i = 0; i < 4; ++i)
            af[i] = *(const bf16x8*)&As[(wm * 64 + i * 16 + l15) * 32 + quad * 8];
#pragma unroll
        for (int j = 0; j < 4; ++j)
            bfr[j] = *(const bf16x8*)&Bs[(wn * 64 + j * 16 + l15) * 32 + quad * 8];
#pragma unroll
        for (int i = 0; i < 4; ++i)
#pragma unroll
            for (int j = 0; j < 4; ++j)
                acc[i][j] = mfma16(af[i], bfr[j], acc[i][j]);
    }

    const int r0 = quad * 4;
#pragma unroll
    for (int j = 0; j < 4; ++j) {
        int col = n0 + wn * 64 + j * 16 + l15;
        float bv = bias[col];
#pragma unroll
        for (int i = 0; i < 4; ++i) {
            int rowb = m0 + wm * 64 + i * 16 + r0;
#pragma unroll
            for (int r = 0; r < 4; ++r) {
                float v = acc[i][j][r] + bv;
                if (do_relu) v = fmaxf(v, 0.f);
                C[(size_t)(rowb + r) * N + col] = f2b(v);
            }
        }
    }
}

// ---------------------------------------------------------------------------
// transpose + f32->bf16 convert: in f32 [R][C] -> out bf16 [C][R]. block (32,8)
// ---------------------------------------------------------------------------
__global__ __launch_bounds__(256) void transpose_cvt(
    const float* __restrict__ in, u16* __restrict__ out, int R, int C)
{
    __shared__ u16 t[32][33];
    int c0 = blockIdx.x * 32, r0 = blockIdx.y * 32;
    int tx = threadIdx.x, ty = threadIdx.y;
#pragma unroll
    for (int i = 0; i < 4; ++i)
        t[ty + i * 8][tx] = f2b(in[(size_t)(r0 + ty + i * 8) * C + c0 + tx]);
    __syncthreads();
#pragma unroll
    for (int i = 0; i < 4; ++i)
        out[(size_t)(c0 + ty + i * 8) * R + r0 + tx] = t[tx][ty + i * 8];
}

// batched bf16 transpose: in [z][R][C] -> out [z][C][R]. block (32,8)
__global__ __launch_bounds__(256) void transpose_b(
    const u16* __restrict__ in, u16* __restrict__ out, int R, int C)
{
    __shared__ u16 t[32][33];
    const u16* ip = in  + (size_t)blockIdx.z * R * C;
    u16*       op = out + (size_t)blockIdx.z * R * C;
    int c0 = blockIdx.x * 32, r0 = blockIdx.y * 32;
    int tx = threadIdx.x, ty = threadIdx.y;
#pragma unroll
    for (int i = 0; i < 4; ++i)
        t[ty + i * 8][tx] = ip[(size_t)(r0 + ty + i * 8) * C + c0 + tx];
    __syncthreads();
#pragma unroll
    for (int i = 0; i < 4; ++i)
        op[(size_t)(c0 + ty + i * 8) * R + r0 + tx] = t[tx][ty + i * 8];
}

// ---------------------------------------------------------------------------
// head: out[row,:] = log_softmax(o[row,:] @ W4 + b4). One wave per row.
// ---------------------------------------------------------------------------
__global__ __launch_bounds__(256) void head_logsoftmax(
    const u16* __restrict__ o, const float* __restrict__ W4,
    const float* __restrict__ b4, float* __restrict__ out)
{
    __shared__ float W4s[DIN * DOUT];
    __shared__ float b4s[DOUT];
    const int tid = threadIdx.x;
    for (int i = tid; i < DIN * DOUT; i += 256) W4s[i] = W4[i];
    if (tid < DOUT) b4s[tid] = b4[tid];
    __syncthreads();
    const int lane = tid & 63, w = tid >> 6;
    const size_t row = (size_t)blockIdx.x * 4 + w;
    const uint4 ov = *(const uint4*)&o[row * DIN + lane * 8];
    const u32* ou = (const u32*)&ov;
    float oc[8];
#pragma unroll
    for (int i = 0; i < 4; ++i) {
        oc[2*i]   = b2f((u16)(ou[i] & 0xFFFFu));
        oc[2*i+1] = b2f((u16)(ou[i] >> 16));
    }
    float acc[DOUT];
#pragma unroll
    for (int c = 0; c < DOUT; ++c) acc[c] = 0.f;
#pragma unroll
    for (int i = 0; i < 8; ++i) {
        int k = lane * 8 + i;
        float x = oc[i];
#pragma unroll
        for (int c = 0; c < DOUT; ++c) acc[c] += x * W4s[k * DOUT + c];
    }
#pragma unroll
    for (int off = 32; off >= 1; off >>= 1)
#pragma unroll
        for (int c = 0; c < DOUT; ++c) acc[c] += __shfl_xor(acc[c], off, 64);
    float mx = -1e30f;
#pragma unroll
    for (int c = 0; c < DOUT; ++c) { acc[c] += b4s[c]; mx = fmaxf(mx, acc[c]); }
    float sum = 0.f;
#pragma unroll
    for (int c = 0; c < DOUT; ++c) sum += __expf(acc[c] - mx);
    float lse = mx + logf(sum);
    if (lane == 0) {
#pragma unroll
        for (int c = 0; c < DOUT; ++c) out[row * DOUT + c] = acc[c] - lse;
    }
}

// ---------------------------------------------------------------------------
extern "C" void kernel_launch(void* const* d_in, const int* in_sizes, int n_in,
                              void* d_out, int out_size, void* d_ws, size_t ws_size,
                              hipStream_t stream) {
    const float* x  = (const float*)d_in[0];
    const float* gv = (const float*)d_in[1];
    const float* uv = (const float*)d_in[2];
    const float* W1 = (const float*)d_in[3];
    const float* b1 = (const float*)d_in[4];
    const float* W2 = (const float*)d_in[5];
    const float* b2 = (const float*)d_in[6];
    const float* W3 = (const float*)d_in[7];
    const float* b3 = (const float*)d_in[8];
    const float* W4 = (const float*)d_in[9];
    const float* b4 = (const float*)d_in[10];
    float* out = (float*)d_out;

    char* ws = (char*)d_ws;
    const size_t MB64 = (size_t)67108864;
    const size_t MiB  = (size_t)1048576;
    // Tier A2: 2 chunks of 8 batches. Footprint:
    //   h1/ctx 64Mi | h/o 64Mi | {xb 32Mi | hT_c 32Mi} + P_c 40Mi | weights 4Mi
    const size_t TIER_A2 = 2 * MB64 + 72 * MiB + 8 * MiB;   // 208 MiB gate
    const size_t TIER_B  = 3 * MB64 + 5 * MiB;              // 197 MiB

    if (ws_size >= TIER_A2) {
        u16* h1   = (u16*)(ws);
        u16* ctx  = h1;
        u16* h    = (u16*)(ws + MB64);
        u16* o    = h;                                  // h dead after attention
        u16* xb   = (u16*)(ws + 2 * MB64);              // 32 Mi, dead after GEMM1
        u16* hT_c = xb;                                 // 32 Mi (8 batches)
        u16* P_c  = (u16*)(ws + 2 * MB64 + 32 * MiB);   // 40 Mi (8 batches packed)
        u16* W1t  = (u16*)(ws + 2 * MB64 + 72 * MiB);
        u16* W2t  = W1t + 512 * 1024;
        u16* W3t  = W2t + 1024 * 1024;

        cvt_f32_bf16<<<8192, 256, 0, stream>>>(x, xb, 2097152);
        transpose_cvt<<<dim3(32, 16), dim3(32, 8), 0, stream>>>(W1, W1t, 512, 1024);
        transpose_cvt<<<dim3(32, 32), dim3(32, 8), 0, stream>>>(W2, W2t, 1024, 1024);
        transpose_cvt<<<dim3(16, 32), dim3(32, 8), 0, stream>>>(W3, W3t, 1024, 512);

        gemm_a<<<dim3(256, 8), 256, 0, stream>>>(xb, W1t, b1, h1, 32768, 1024, 512, 1);
        gemm_a<<<dim3(256, 8), 256, 0, stream>>>(h1, W2t, b2, h,  32768, 1024, 1024, 1);

        // attention in 2 chunks of 8 batches
        for (int c = 0; c < 2; ++c) {
            const u16* hc  = h   + (size_t)c * 8 * S_ * DH;
            u16*       cxc = ctx + (size_t)c * 8 * S_ * DH;
            transpose_b<<<dim3(32, 64, 8), dim3(32, 8), 0, stream>>>(hc, hT_c, 2048, 1024);
            score_a<<<dim3(16, 16, 8), 256, 0, stream>>>(hc, P_c);
            softmax_rows<<<4096, 256, 0, stream>>>(P_c);
            pv_a<<<dim3(16, 8, 8), 256, 0, stream>>>(P_c, hT_c, cxc);
        }

        gemm_a<<<dim3(256, 4), 256, 0, stream>>>(ctx, W3t, b3, o, 32768, 512, 1024, 1);
        head_logsoftmax<<<8192, 256, 0, stream>>>(o, W4, b4, out);
    } else if (ws_size >= TIER_B) {
        // 4-chunk attention (4 batches each), packed P
        u16* h1   = (u16*)(ws);
        u16* ctx  = h1;
        u16* h    = (u16*)(ws + MB64);
        u16* xb   = (u16*)(ws + 2 * MB64);
        u16* hT_c = xb;                                  // 16 Mi (4 batches)
        u16* P_c  = (u16*)(ws + 2 * MB64 + 16 * MiB);    // 20 Mi (4 batches packed)
        u16* o    = (u16*)(ws + 2 * MB64);
        u16* W1t  = (u16*)(ws + 3 * MB64);
        u16* W2t  = W1t + 512 * 1024;
        u16* W3t  = W2t + 1024 * 1024;

        cvt_f32_bf16<<<8192, 256, 0, stream>>>(x, xb, 2097152);
        transpose_cvt<<<dim3(32, 16), dim3(32, 8), 0, stream>>>(W1, W1t, 512, 1024);
        transpose_cvt<<<dim3(32, 32), dim3(32, 8), 0, stream>>>(W2, W2t, 1024, 1024);
        transpose_cvt<<<dim3(16, 32), dim3(32, 8), 0, stream>>>(W3, W3t, 1024, 512);

        gemm_a<<<dim3(256, 8), 256, 0, stream>>>(xb, W1t, b1, h1, 32768, 1024, 512, 1);
        gemm_a<<<dim3(256, 8), 256, 0, stream>>>(h1, W2t, b2, h,  32768, 1024, 1024, 1);

        for (int c = 0; c < 4; ++c) {
            const u16* hc  = h   + (size_t)c * 4 * S_ * DH;
            u16*       cxc = ctx + (size_t)c * 4 * S_ * DH;
            transpose_b<<<dim3(32, 64, 4), dim3(32, 8), 0, stream>>>(hc, hT_c, 2048, 1024);
            score_a<<<dim3(16, 16, 4), 256, 0, stream>>>(hc, P_c);
            softmax_rows<<<2048, 256, 0, stream>>>(P_c);
            pv_a<<<dim3(16, 8, 4), 256, 0, stream>>>(P_c, hT_c, cxc);
        }

        gemm_a<<<dim3(256, 4), 256, 0, stream>>>(ctx, W3t, b3, o, 32768, 512, 1024, 1);
        head_logsoftmax<<<8192, 256, 0, stream>>>(o, W4, b4, out);
    } else {
        // Compact fallback (~86 MiB): per-batch attention through small scratch
        u16* h    = (u16*)(ws);                          // 64 Mi
        u16* hT_b = (u16*)(ws + MB64);                   // 4 Mi
        u16* P_b  = (u16*)(ws + MB64 + 4 * MiB);         // 8 Mi (packed uses 5)
        u16* ctx_b= (u16*)(ws + MB64 + 12 * MiB);        // 4 Mi
        u16* o_b  = (u16*)(ws + MB64 + 16 * MiB);        // 2 Mi
        u16* W1t  = (u16*)(ws + MB64 + 18 * MiB);
        u16* W2t  = W1t + 512 * 1024;
        u16* W3t  = W2t + 1024 * 1024;
        u16* h1_b = P_b;

        transpose_cvt<<<dim3(32, 16), dim3(32, 8), 0, stream>>>(W1, W1t, 512, 1024);
        transpose_cvt<<<dim3(32, 32), dim3(32, 8), 0, stream>>>(W2, W2t, 1024, 1024);
        transpose_cvt<<<dim3(16, 32), dim3(32, 8), 0, stream>>>(W3, W3t, 1024, 512);

        for (int c = 0; c < 8; ++c) {
            const float* xc = x + (size_t)c * 4096 * DIN;
            u16*         hc = h + (size_t)c * 4096 * DH;
            gemm_bt_bias_relu<true ><<<dim3(32, 8), 256, 0, stream>>>(xc, W1t, b1, h1_b,
                                                                      4096, 1024, 512, 1);
            gemm_bt_bias_relu<false><<<dim3(32, 8), 256, 0, stream>>>(h1_b, W2t, b2, hc,
                                                                      4096, 1024, 1024, 1);
        }
        for (int b = 0; b < B_; ++b) {
            const u16* hb = h + (size_t)b * S_ * DH;
            transpose_b<<<dim3(32, 64, 1), dim3(32, 8), 0, stream>>>(hb, hT_b, 2048, 1024);
            score_a<<<dim3(16, 16, 1), 256, 0, stream>>>(hb, P_b);
            softmax_rows<<<512, 256, 0, stream>>>(P_b);
            pv_a<<<dim3(16, 8, 1), 256, 0, stream>>>(P_b, hT_b, ctx_b);
            gemm_bt_bias_relu<false><<<dim3(16, 4), 256, 0, stream>>>(ctx_b, W3t, b3, o_b,
                                                                      2048, 512, 1024, 1);
            head_logsoftmax<<<512, 256, 0, stream>>>(o_b, W4, b4,
                                                     out + (size_t)b * S_ * DOUT);
        }
    }

    // pass-throughs (f32)
    size_t n_gv = (size_t)in_sizes[1], n_uv = (size_t)in_sizes[2];
    size_t o0 = (size_t)out_size - n_gv - n_uv;
    hipMemcpyAsync(out + o0,        gv, n_gv * 4, hipMemcpyDeviceToDevice, stream);
    hipMemcpyAsync(out + o0 + n_gv, uv, n_uv * 4, hipMemcpyDeviceToDevice, stream);
}

// Round 10
// 761.283 us; speedup vs baseline: 1.1445x; 1.0787x over previous
//
#include <hip/hip_runtime.h>
#include <stdint.h>

// Problem constants (fixed by reference)
#define B_   16
#define S_   2048
#define DIN  512
#define DH   1024
#define DOUT 10

typedef unsigned short u16;
typedef unsigned int   u32;

typedef __bf16 bf16_t;
typedef bf16_t bf16x8 __attribute__((ext_vector_type(8)));
typedef float  f32x4  __attribute__((ext_vector_type(4)));

#define MASKVAL (-3.0e4f)
// Packed-P geometry: row-block mi holds r4 = ((mi>>2)+1)*4 tiles of 128 cols.
// Tile-offset of row-block mi: S4(mi) = 4*(g+1)*(mi-2g), g = mi>>2.
// Per-batch packed size = 160 tiles * 16384 u16 = 5 MiB.
#define PZ_U16 ((size_t)160 * 16384)

__device__ __forceinline__ float b2f(u16 u) {
    union { u32 i; float f; } v; v.i = ((u32)u) << 16; return v.f;
}
__device__ __forceinline__ u16 f2b(float f) {
    union { float f; u32 i; } v; v.f = f;
    u32 u = v.i;
    u32 r = (u + 0x7FFFu + ((u >> 16) & 1u)) >> 16;  // RNE
    return (u16)r;
}
__device__ __forceinline__ u32 pack2(float a, float b) {
    return (u32)f2b(a) | ((u32)f2b(b) << 16);
}

__device__ __forceinline__ f32x4 mfma16(bf16x8 a, bf16x8 b, f32x4 c) {
    return __builtin_amdgcn_mfma_f32_16x16x32_bf16(a, b, c, 0, 0, 0);
}

// async global->LDS, 16B per lane; LDS dest = wave-uniform base + lane*16
__device__ __forceinline__ void load_lds16(const u16* g, u16* l) {
    __builtin_amdgcn_global_load_lds(
        (__attribute__((address_space(1))) u32*)(g),
        (__attribute__((address_space(3))) u32*)(l), 16, 0, 0);
}

// load 8 contiguous elements at element-index eidx as packed bf16x8 (uint4)
template<bool F32>
__device__ __forceinline__ uint4 ld8(const void* base, size_t eidx) {
    if constexpr (F32) {
        const float* p = (const float*)base + eidx;
        float4 f0 = *(const float4*)p;
        float4 f1 = *(const float4*)(p + 4);
        uint4 r;
        r.x = pack2(f0.x, f0.y); r.y = pack2(f0.z, f0.w);
        r.z = pack2(f1.x, f1.y); r.w = pack2(f1.z, f1.w);
        return r;
    } else {
        return *(const uint4*)((const u16*)base + eidx);
    }
}

// ---------------------------------------------------------------------------
// f32 -> bf16 elementwise convert (8 elems/thread)
// ---------------------------------------------------------------------------
__global__ __launch_bounds__(256) void cvt_f32_bf16(
    const float* __restrict__ in, u16* __restrict__ out, int n8)
{
    int i = blockIdx.x * 256 + threadIdx.x;
    if (i >= n8) return;
    size_t e = (size_t)i * 8;
    float4 f0 = *(const float4*)(in + e);
    float4 f1 = *(const float4*)(in + e + 4);
    uint4 r;
    r.x = pack2(f0.x, f0.y); r.y = pack2(f0.z, f0.w);
    r.z = pack2(f1.x, f1.y); r.w = pack2(f1.z, f1.w);
    *(uint4*)(out + e) = r;
}

// ---------------------------------------------------------------------------
// ASYNC-staged GEMM: C[M,N] = relu(A[M,K] @ Bt[N,K]^T + bias[N]), all bf16.
// grid x = M/128 (m-fast, round-6 proven), y = N/128.
// ---------------------------------------------------------------------------
__global__ __launch_bounds__(256) void gemm_a(
    const u16* __restrict__ A, const u16* __restrict__ Bt,
    const float* __restrict__ bias, u16* __restrict__ C,
    int M, int N, int K, int do_relu)
{
    __shared__ __attribute__((aligned(16))) u16 As[128 * 32];
    __shared__ __attribute__((aligned(16))) u16 Bs[128 * 32];

    const int tid  = threadIdx.x;
    const int lane = tid & 63;
    const int w    = tid >> 6;
    const int wm   = w >> 1, wn = w & 1;
    const int quad = lane >> 4, l15 = lane & 15;

    const int m0 = blockIdx.x * 128;
    const int n0 = blockIdx.y * 128;

    const int c0 = tid, c1 = tid + 256;
    const u16* gA0 = A  + ((size_t)(m0 + (c0 >> 2)) * K + (c0 & 3) * 8);
    const u16* gA1 = A  + ((size_t)(m0 + (c1 >> 2)) * K + (c1 & 3) * 8);
    const u16* gB0 = Bt + ((size_t)(n0 + (c0 >> 2)) * K + (c0 & 3) * 8);
    const u16* gB1 = Bt + ((size_t)(n0 + (c1 >> 2)) * K + (c1 & 3) * 8);
    u16* lA0 = &As[(w * 64) * 8];
    u16* lA1 = &As[(256 + w * 64) * 8];
    u16* lB0 = &Bs[(w * 64) * 8];
    u16* lB1 = &Bs[(256 + w * 64) * 8];

    f32x4 acc[4][4];
#pragma unroll
    for (int i = 0; i < 4; ++i)
#pragma unroll
        for (int j = 0; j < 4; ++j) acc[i][j] = (f32x4){0.f, 0.f, 0.f, 0.f};

    const int nk = K >> 5;
    for (int kk = 0; kk < nk; ++kk) {
        load_lds16(gA0, lA0); load_lds16(gA1, lA1);
        load_lds16(gB0, lB0); load_lds16(gB1, lB1);
        gA0 += 32; gA1 += 32; gB0 += 32; gB1 += 32;
        __syncthreads();
        bf16x8 af[4], bfr[4];
#pragma unroll
        for (int i = 0; i < 4; ++i)
            af[i] = *(const bf16x8*)&As[(wm * 64 + i * 16 + l15) * 32 + quad * 8];
#pragma unroll
        for (int j = 0; j < 4; ++j)
            bfr[j] = *(const bf16x8*)&Bs[(wn * 64 + j * 16 + l15) * 32 + quad * 8];
#pragma unroll
        for (int i = 0; i < 4; ++i)
#pragma unroll
            for (int j = 0; j < 4; ++j)
                acc[i][j] = mfma16(af[i], bfr[j], acc[i][j]);
        __syncthreads();
    }

    const int r0 = quad * 4;
#pragma unroll
    for (int j = 0; j < 4; ++j) {
        int col = n0 + wn * 64 + j * 16 + l15;
        float bv = bias[col];
#pragma unroll
        for (int i = 0; i < 4; ++i) {
            int rowb = m0 + wm * 64 + i * 16 + r0;
#pragma unroll
            for (int r = 0; r < 4; ++r) {
                float v = acc[i][j][r] + bv;
                if (do_relu) v = fmaxf(v, 0.f);
                C[(size_t)(rowb + r) * N + col] = f2b(v);
            }
        }
    }
}

// ---------------------------------------------------------------------------
// ASYNC score GEMM into PACKED P: row-block mi = causal tiles ni<=mi,
// padded to r4 tiles; pad tiles get MASKVAL. grid (16, 16, nb).
// Heavy row-blocks dispatch first (mi = 15 - blockIdx.x).
// ---------------------------------------------------------------------------
__global__ __launch_bounds__(256) void score_a(
    const u16* __restrict__ h, u16* __restrict__ P)
{
    __shared__ __attribute__((aligned(16))) u16 As[128 * 32];
    __shared__ __attribute__((aligned(16))) u16 Bs[128 * 32];

    const int mi = 15 - blockIdx.x;              // LPT: heavy rows first
    const int ni = blockIdx.y;
    const int g  = mi >> 2;
    const int r4 = (g + 1) * 4;
    if (ni >= r4) return;

    const int tid = threadIdx.x;
    u16* Pz = P + (size_t)blockIdx.z * PZ_U16
                + (size_t)(4 * (g + 1) * (mi - 2 * g)) * 16384;
    const size_t rstride = (size_t)r4 * 128;

    if (ni > mi) {                               // pad tile: MASKVAL fill
        const u16 mb = f2b(MASKVAL);
        const u32 m2 = (u32)mb | ((u32)mb << 16);
        uint4 mv; mv.x = m2; mv.y = m2; mv.z = m2; mv.w = m2;
#pragma unroll
        for (int i = 0; i < 8; ++i) {
            int q = tid + i * 256;
            int row = q >> 4, cl = (q & 15) * 8;
            *(uint4*)&Pz[(size_t)row * rstride + ni * 128 + cl] = mv;
        }
        return;
    }

    const int m0 = mi * 128, n0 = ni * 128;
    const u16* A = h + (size_t)blockIdx.z * S_ * DH;

    const int lane = tid & 63;
    const int w    = tid >> 6;
    const int wm   = w >> 1, wn = w & 1;
    const int quad = lane >> 4, l15 = lane & 15;

    const int c0 = tid, c1 = tid + 256;
    const u16* gA0 = A + ((size_t)(m0 + (c0 >> 2)) * DH + (c0 & 3) * 8);
    const u16* gA1 = A + ((size_t)(m0 + (c1 >> 2)) * DH + (c1 & 3) * 8);
    const u16* gB0 = A + ((size_t)(n0 + (c0 >> 2)) * DH + (c0 & 3) * 8);
    const u16* gB1 = A + ((size_t)(n0 + (c1 >> 2)) * DH + (c1 & 3) * 8);
    u16* lA0 = &As[(w * 64) * 8];
    u16* lA1 = &As[(256 + w * 64) * 8];
    u16* lB0 = &Bs[(w * 64) * 8];
    u16* lB1 = &Bs[(256 + w * 64) * 8];

    f32x4 acc[4][4];
#pragma unroll
    for (int i = 0; i < 4; ++i)
#pragma unroll
        for (int j = 0; j < 4; ++j) acc[i][j] = (f32x4){0.f, 0.f, 0.f, 0.f};

    const int nk = DH >> 5;
    for (int kk = 0; kk < nk; ++kk) {
        load_lds16(gA0, lA0); load_lds16(gA1, lA1);
        load_lds16(gB0, lB0); load_lds16(gB1, lB1);
        gA0 += 32; gA1 += 32; gB0 += 32; gB1 += 32;
        __syncthreads();
        bf16x8 af[4], bfr[4];
#pragma unroll
        for (int i = 0; i < 4; ++i)
            af[i] = *(const bf16x8*)&As[(wm * 64 + i * 16 + l15) * 32 + quad * 8];
#pragma unroll
        for (int j = 0; j < 4; ++j)
            bfr[j] = *(const bf16x8*)&Bs[(wn * 64 + j * 16 + l15) * 32 + quad * 8];
#pragma unroll
        for (int i = 0; i < 4; ++i)
#pragma unroll
            for (int j = 0; j < 4; ++j)
                acc[i][j] = mfma16(af[i], bfr[j], acc[i][j]);
        __syncthreads();
    }

    const int r0 = quad * 4;
#pragma unroll
    for (int j = 0; j < 4; ++j) {
        int cl = wn * 64 + j * 16 + l15;
#pragma unroll
        for (int i = 0; i < 4; ++i) {
            int rl = wm * 64 + i * 16 + r0;
#pragma unroll
            for (int r = 0; r < 4; ++r) {
                int row = rl + r;
                float v = (n0 + cl <= m0 + row) ? acc[i][j][r] : MASKVAL;
                Pz[(size_t)row * rstride + ni * 128 + cl] = f2b(v);
            }
        }
    }
}

// ---------------------------------------------------------------------------
// softmax_rows: in-place row softmax of packed P. One wave per row.
// Row length = kb*512 cols (kb = (mi>>2)+1), includes MASKVAL padding.
// ---------------------------------------------------------------------------
__global__ __launch_bounds__(256) void softmax_rows(u16* __restrict__ P)
{
    const int tid = threadIdx.x;
    const int lane = tid & 63, w = tid >> 6;
    const size_t row = (size_t)blockIdx.x * 4 + w;
    const int z    = (int)(row >> 11);
    const int rloc = (int)(row & (S_ - 1));
    const int mi = rloc >> 7, g = mi >> 2;
    const int kb = g + 1;
    u16* p = P + (size_t)z * PZ_U16
               + (size_t)(4 * (g + 1) * (mi - 2 * g)) * 16384
               + (size_t)(rloc & 127) * ((g + 1) * 4 * 128);
    float v[32];
    float m = -1e30f;
    for (int k = 0; k < kb; ++k) {
        uint4 u = *(const uint4*)&p[k * 512 + lane * 8];
        const u32* uu = (const u32*)&u;
#pragma unroll
        for (int i = 0; i < 4; ++i) {
            float a = b2f((u16)(uu[i] & 0xFFFFu));
            float b = b2f((u16)(uu[i] >> 16));
            v[k * 8 + 2 * i] = a; v[k * 8 + 2 * i + 1] = b;
            m = fmaxf(m, fmaxf(a, b));
        }
    }
#pragma unroll
    for (int off = 32; off >= 1; off >>= 1) m = fmaxf(m, __shfl_xor(m, off, 64));
    float s = 0.f;
    for (int k = 0; k < kb; ++k)
#pragma unroll
        for (int i = 0; i < 8; ++i) {
            float e = __expf(v[k * 8 + i] - m);
            v[k * 8 + i] = e; s += e;
        }
#pragma unroll
    for (int off = 32; off >= 1; off >>= 1) s += __shfl_xor(s, off, 64);
    float inv = 1.0f / s;
    for (int k = 0; k < kb; ++k) {
        uint4 u; u32* uu = (u32*)&u;
#pragma unroll
        for (int i = 0; i < 4; ++i)
            uu[i] = pack2(v[k * 8 + 2 * i] * inv, v[k * 8 + 2 * i + 1] * inv);
        *(uint4*)&p[k * 512 + lane * 8] = u;
    }
}

// ---------------------------------------------------------------------------
// ASYNC pv GEMM, LPT 1D grid: ctx[z] = P[z] @ V[z]; A = packed P, Bt = hT.
// grid.x = 16*8*nb; idx -> mi = 15 - idx/(8*nb) (heavy blocks dispatch FIRST),
// sub = idx%(8*nb): n = sub&7, z = sub>>3. nk = (mi+1)*4.
// ---------------------------------------------------------------------------
__global__ __launch_bounds__(256) void pv_a(
    const u16* __restrict__ P, const u16* __restrict__ hT, u16* __restrict__ ctx,
    int nb)
{
    __shared__ __attribute__((aligned(16))) u16 As[128 * 32];
    __shared__ __attribute__((aligned(16))) u16 Bs[128 * 32];

    const int idx = blockIdx.x;
    const int per_mi = 8 * nb;
    const int mi = 15 - (idx / per_mi);          // LPT: heavy row-blocks first
    const int sub = idx % per_mi;
    const int nblk = sub & 7;
    const int z    = sub >> 3;
    const int g = mi >> 2;
    const int m0 = mi * 128;
    const int n0 = nblk * 128;
    const size_t rstride = (size_t)((g + 1) * 4) * 128;
    const u16* A  = P  + (size_t)z * PZ_U16
                       + (size_t)(4 * (g + 1) * (mi - 2 * g)) * 16384;
    const u16* Bt = hT + (size_t)z * DH * S_;
    u16*      C   = ctx + (size_t)z * S_ * DH;

    const int tid  = threadIdx.x;
    const int lane = tid & 63;
    const int w    = tid >> 6;
    const int wm   = w >> 1, wn = w & 1;
    const int quad = lane >> 4, l15 = lane & 15;

    const int c0 = tid, c1 = tid + 256;
    const u16* gA0 = A  + ((size_t)(c0 >> 2) * rstride + (c0 & 3) * 8);
    const u16* gA1 = A  + ((size_t)(c1 >> 2) * rstride + (c1 & 3) * 8);
    const u16* gB0 = Bt + ((size_t)(n0 + (c0 >> 2)) * S_ + (c0 & 3) * 8);
    const u16* gB1 = Bt + ((size_t)(n0 + (c1 >> 2)) * S_ + (c1 & 3) * 8);
    u16* lA0 = &As[(w * 64) * 8];
    u16* lA1 = &As[(256 + w * 64) * 8];
    u16* lB0 = &Bs[(w * 64) * 8];
    u16* lB1 = &Bs[(256 + w * 64) * 8];

    f32x4 acc[4][4];
#pragma unroll
    for (int i = 0; i < 4; ++i)
#pragma unroll
        for (int j = 0; j < 4; ++j) acc[i][j] = (f32x4){0.f, 0.f, 0.f, 0.f};

    const int nk = (mi + 1) * 4;
    for (int kk = 0; kk < nk; ++kk) {
        load_lds16(gA0, lA0); load_lds16(gA1, lA1);
        load_lds16(gB0, lB0); load_lds16(gB1, lB1);
        gA0 += 32; gA1 += 32; gB0 += 32; gB1 += 32;
        __syncthreads();
        bf16x8 af[4], bfr[4];
#pragma unroll
        for (int i = 0; i < 4; ++i)
            af[i] = *(const bf16x8*)&As[(wm * 64 + i * 16 + l15) * 32 + quad * 8];
#pragma unroll
        for (int j = 0; j < 4; ++j)
            bfr[j] = *(const bf16x8*)&Bs[(wn * 64 + j * 16 + l15) * 32 + quad * 8];
#pragma unroll
        for (int i = 0; i < 4; ++i)
#pragma unroll
            for (int j = 0; j < 4; ++j)
                acc[i][j] = mfma16(af[i], bfr[j], acc[i][j]);
        __syncthreads();
    }

    const int r0 = quad * 4;
#pragma unroll
    for (int j = 0; j < 4; ++j) {
        int col = n0 + wn * 64 + j * 16 + l15;
#pragma unroll
        for (int i = 0; i < 4; ++i) {
            int rowb = m0 + wm * 64 + i * 16 + r0;
#pragma unroll
            for (int r = 0; r < 4; ++r)
                C[(size_t)(rowb + r) * DH + col] = f2b(acc[i][j][r]);
        }
    }
}

// ---------------------------------------------------------------------------
// SYNC-staged GEMM (tier-C fallback only; A may be f32)
// ---------------------------------------------------------------------------
template<bool AF32>
__global__ __launch_bounds__(256) void gemm_bt_bias_relu(
    const void* __restrict__ A, const u16* __restrict__ Bt,
    const float* __restrict__ bias, u16* __restrict__ C,
    int M, int N, int K, int do_relu)
{
    __shared__ __attribute__((aligned(16))) u16 As[128 * 32];
    __shared__ __attribute__((aligned(16))) u16 Bs[128 * 32];

    const int tid  = threadIdx.x;
    const int lane = tid & 63;
    const int w    = tid >> 6;
    const int wm   = w >> 1, wn = w & 1;
    const int quad = lane >> 4, l15 = lane & 15;

    const int m0 = blockIdx.x * 128;
    const int n0 = blockIdx.y * 128;

    const int c0 = tid, c1 = tid + 256;
    size_t eA0 = (size_t)(m0 + (c0 >> 2)) * K + (c0 & 3) * 8;
    size_t eA1 = (size_t)(m0 + (c1 >> 2)) * K + (c1 & 3) * 8;
    size_t eB0 = (size_t)(n0 + (c0 >> 2)) * K + (c0 & 3) * 8;
    size_t eB1 = (size_t)(n0 + (c1 >> 2)) * K + (c1 & 3) * 8;

    f32x4 acc[4][4];
#pragma unroll
    for (int i = 0; i < 4; ++i)
#pragma unroll
        for (int j = 0; j < 4; ++j) acc[i][j] = (f32x4){0.f, 0.f, 0.f, 0.f};

    uint4 va0 = ld8<AF32>(A, eA0), va1 = ld8<AF32>(A, eA1);
    uint4 vb0 = ld8<false>(Bt, eB0), vb1 = ld8<false>(Bt, eB1);

    const int nk = K >> 5;
    for (int kk = 0; kk < nk; ++kk) {
        __syncthreads();
        *(uint4*)&As[c0 * 8] = va0;
        *(uint4*)&As[c1 * 8] = va1;
        *(uint4*)&Bs[c0 * 8] = vb0;
        *(uint4*)&Bs[c1 * 8] = vb1;
        if (kk + 1 < nk) {
            eA0 += 32; eA1 += 32; eB0 += 32; eB1 += 32;
            va0 = ld8<AF32>(A, eA0); va1 = ld8<AF32>(A, eA1);
            vb0 = ld8<false>(Bt, eB0); vb1 = ld8<false>(Bt, eB1);
        }
        __syncthreads();
        bf16x8 af[4], bfr[4];
#pragma unroll
        for (int i = 0; i < 4; ++i)
            af[i] = *(const bf16x8*)&As[(wm * 64 + i * 16 + l15) * 32 + quad * 8];
#pragma unroll
        for (int j = 0; j < 4; ++j)
            bfr[j] = *(const bf16x8*)&Bs[(wn * 64 + j * 16 + l15) * 32 + quad * 8];
#pragma unroll
        for (int i = 0; i < 4; ++i)
#pragma unroll
            for (int j = 0; j < 4; ++j)
                acc[i][j] = mfma16(af[i], bfr[j], acc[i][j]);
    }

    const int r0 = quad * 4;
#pragma unroll
    for (int j = 0; j < 4; ++j) {
        int col = n0 + wn * 64 + j * 16 + l15;
        float bv = bias[col];
#pragma unroll
        for (int i = 0; i < 4; ++i) {
            int rowb = m0 + wm * 64 + i * 16 + r0;
#pragma unroll
            for (int r = 0; r < 4; ++r) {
                float v = acc[i][j][r] + bv;
                if (do_relu) v = fmaxf(v, 0.f);
                C[(size_t)(rowb + r) * N + col] = f2b(v);
            }
        }
    }
}

// ---------------------------------------------------------------------------
// transpose + f32->bf16 convert: in f32 [R][C] -> out bf16 [C][R]. block (32,8)
// ---------------------------------------------------------------------------
__global__ __launch_bounds__(256) void transpose_cvt(
    const float* __restrict__ in, u16* __restrict__ out, int R, int C)
{
    __shared__ u16 t[32][33];
    int c0 = blockIdx.x * 32, r0 = blockIdx.y * 32;
    int tx = threadIdx.x, ty = threadIdx.y;
#pragma unroll
    for (int i = 0; i < 4; ++i)
        t[ty + i * 8][tx] = f2b(in[(size_t)(r0 + ty + i * 8) * C + c0 + tx]);
    __syncthreads();
#pragma unroll
    for (int i = 0; i < 4; ++i)
        out[(size_t)(c0 + ty + i * 8) * R + r0 + tx] = t[tx][ty + i * 8];
}

// batched bf16 transpose: in [z][R][C] -> out [z][C][R]. block (32,8)
__global__ __launch_bounds__(256) void transpose_b(
    const u16* __restrict__ in, u16* __restrict__ out, int R, int C)
{
    __shared__ u16 t[32][33];
    const u16* ip = in  + (size_t)blockIdx.z * R * C;
    u16*       op = out + (size_t)blockIdx.z * R * C;
    int c0 = blockIdx.x * 32, r0 = blockIdx.y * 32;
    int tx = threadIdx.x, ty = threadIdx.y;
#pragma unroll
    for (int i = 0; i < 4; ++i)
        t[ty + i * 8][tx] = ip[(size_t)(r0 + ty + i * 8) * C + c0 + tx];
    __syncthreads();
#pragma unroll
    for (int i = 0; i < 4; ++i)
        op[(size_t)(c0 + ty + i * 8) * R + r0 + tx] = t[tx][ty + i * 8];
}

// ---------------------------------------------------------------------------
// head: out[row,:] = log_softmax(o[row,:] @ W4 + b4). One wave per row.
// ---------------------------------------------------------------------------
__global__ __launch_bounds__(256) void head_logsoftmax(
    const u16* __restrict__ o, const float* __restrict__ W4,
    const float* __restrict__ b4, float* __restrict__ out)
{
    __shared__ float W4s[DIN * DOUT];
    __shared__ float b4s[DOUT];
    const int tid = threadIdx.x;
    for (int i = tid; i < DIN * DOUT; i += 256) W4s[i] = W4[i];
    if (tid < DOUT) b4s[tid] = b4[tid];
    __syncthreads();
    const int lane = tid & 63, w = tid >> 6;
    const size_t row = (size_t)blockIdx.x * 4 + w;
    const uint4 ov = *(const uint4*)&o[row * DIN + lane * 8];
    const u32* ou = (const u32*)&ov;
    float oc[8];
#pragma unroll
    for (int i = 0; i < 4; ++i) {
        oc[2*i]   = b2f((u16)(ou[i] & 0xFFFFu));
        oc[2*i+1] = b2f((u16)(ou[i] >> 16));
    }
    float acc[DOUT];
#pragma unroll
    for (int c = 0; c < DOUT; ++c) acc[c] = 0.f;
#pragma unroll
    for (int i = 0; i < 8; ++i) {
        int k = lane * 8 + i;
        float x = oc[i];
#pragma unroll
        for (int c = 0; c < DOUT; ++c) acc[c] += x * W4s[k * DOUT + c];
    }
#pragma unroll
    for (int off = 32; off >= 1; off >>= 1)
#pragma unroll
        for (int c = 0; c < DOUT; ++c) acc[c] += __shfl_xor(acc[c], off, 64);
    float mx = -1e30f;
#pragma unroll
    for (int c = 0; c < DOUT; ++c) { acc[c] += b4s[c]; mx = fmaxf(mx, acc[c]); }
    float sum = 0.f;
#pragma unroll
    for (int c = 0; c < DOUT; ++c) sum += __expf(acc[c] - mx);
    float lse = mx + logf(sum);
    if (lane == 0) {
#pragma unroll
        for (int c = 0; c < DOUT; ++c) out[row * DOUT + c] = acc[c] - lse;
    }
}

// ---------------------------------------------------------------------------
extern "C" void kernel_launch(void* const* d_in, const int* in_sizes, int n_in,
                              void* d_out, int out_size, void* d_ws, size_t ws_size,
                              hipStream_t stream) {
    const float* x  = (const float*)d_in[0];
    const float* gv = (const float*)d_in[1];
    const float* uv = (const float*)d_in[2];
    const float* W1 = (const float*)d_in[3];
    const float* b1 = (const float*)d_in[4];
    const float* W2 = (const float*)d_in[5];
    const float* b2 = (const float*)d_in[6];
    const float* W3 = (const float*)d_in[7];
    const float* b3 = (const float*)d_in[8];
    const float* W4 = (const float*)d_in[9];
    const float* b4 = (const float*)d_in[10];
    float* out = (float*)d_out;

    char* ws = (char*)d_ws;
    const size_t MB64 = (size_t)67108864;
    const size_t MiB  = (size_t)1048576;
    const size_t TIER_A2 = 2 * MB64 + 72 * MiB + 8 * MiB;   // 208 MiB gate
    const size_t TIER_B  = 3 * MB64 + 5 * MiB;              // 197 MiB

    if (ws_size >= TIER_A2) {
        u16* h1   = (u16*)(ws);
        u16* ctx  = h1;
        u16* h    = (u16*)(ws + MB64);
        u16* o    = h;
        u16* xb   = (u16*)(ws + 2 * MB64);
        u16* hT_c = xb;
        u16* P_c  = (u16*)(ws + 2 * MB64 + 32 * MiB);
        u16* W1t  = (u16*)(ws + 2 * MB64 + 72 * MiB);
        u16* W2t  = W1t + 512 * 1024;
        u16* W3t  = W2t + 1024 * 1024;

        cvt_f32_bf16<<<8192, 256, 0, stream>>>(x, xb, 2097152);
        transpose_cvt<<<dim3(32, 16), dim3(32, 8), 0, stream>>>(W1, W1t, 512, 1024);
        transpose_cvt<<<dim3(32, 32), dim3(32, 8), 0, stream>>>(W2, W2t, 1024, 1024);
        transpose_cvt<<<dim3(16, 32), dim3(32, 8), 0, stream>>>(W3, W3t, 1024, 512);

        gemm_a<<<dim3(256, 8), 256, 0, stream>>>(xb, W1t, b1, h1, 32768, 1024, 512, 1);
        gemm_a<<<dim3(256, 8), 256, 0, stream>>>(h1, W2t, b2, h,  32768, 1024, 1024, 1);

        for (int c = 0; c < 2; ++c) {
            const u16* hc  = h   + (size_t)c * 8 * S_ * DH;
            u16*       cxc = ctx + (size_t)c * 8 * S_ * DH;
            transpose_b<<<dim3(32, 64, 8), dim3(32, 8), 0, stream>>>(hc, hT_c, 2048, 1024);
            score_a<<<dim3(16, 16, 8), 256, 0, stream>>>(hc, P_c);
            softmax_rows<<<4096, 256, 0, stream>>>(P_c);
            pv_a<<<16 * 8 * 8, 256, 0, stream>>>(P_c, hT_c, cxc, 8);
        }

        gemm_a<<<dim3(256, 4), 256, 0, stream>>>(ctx, W3t, b3, o, 32768, 512, 1024, 1);
        head_logsoftmax<<<8192, 256, 0, stream>>>(o, W4, b4, out);
    } else if (ws_size >= TIER_B) {
        u16* h1   = (u16*)(ws);
        u16* ctx  = h1;
        u16* h    = (u16*)(ws + MB64);
        u16* xb   = (u16*)(ws + 2 * MB64);
        u16* hT_c = xb;
        u16* P_c  = (u16*)(ws + 2 * MB64 + 16 * MiB);
        u16* o    = (u16*)(ws + 2 * MB64);
        u16* W1t  = (u16*)(ws + 3 * MB64);
        u16* W2t  = W1t + 512 * 1024;
        u16* W3t  = W2t + 1024 * 1024;

        cvt_f32_bf16<<<8192, 256, 0, stream>>>(x, xb, 2097152);
        transpose_cvt<<<dim3(32, 16), dim3(32, 8), 0, stream>>>(W1, W1t, 512, 1024);
        transpose_cvt<<<dim3(32, 32), dim3(32, 8), 0, stream>>>(W2, W2t, 1024, 1024);
        transpose_cvt<<<dim3(16, 32), dim3(32, 8), 0, stream>>>(W3, W3t, 1024, 512);

        gemm_a<<<dim3(256, 8), 256, 0, stream>>>(xb, W1t, b1, h1, 32768, 1024, 512, 1);
        gemm_a<<<dim3(256, 8), 256, 0, stream>>>(h1, W2t, b2, h,  32768, 1024, 1024, 1);

        for (int c = 0; c < 4; ++c) {
            const u16* hc  = h   + (size_t)c * 4 * S_ * DH;
            u16*       cxc = ctx + (size_t)c * 4 * S_ * DH;
            transpose_b<<<dim3(32, 64, 4), dim3(32, 8), 0, stream>>>(hc, hT_c, 2048, 1024);
            score_a<<<dim3(16, 16, 4), 256, 0, stream>>>(hc, P_c);
            softmax_rows<<<2048, 256, 0, stream>>>(P_c);
            pv_a<<<16 * 8 * 4, 256, 0, stream>>>(P_c, hT_c, cxc, 4);
        }

        gemm_a<<<dim3(256, 4), 256, 0, stream>>>(ctx, W3t, b3, o, 32768, 512, 1024, 1);
        head_logsoftmax<<<8192, 256, 0, stream>>>(o, W4, b4, out);
    } else {
        u16* h    = (u16*)(ws);
        u16* hT_b = (u16*)(ws + MB64);
        u16* P_b  = (u16*)(ws + MB64 + 4 * MiB);
        u16* ctx_b= (u16*)(ws + MB64 + 12 * MiB);
        u16* o_b  = (u16*)(ws + MB64 + 16 * MiB);
        u16* W1t  = (u16*)(ws + MB64 + 18 * MiB);
        u16* W2t  = W1t + 512 * 1024;
        u16* W3t  = W2t + 1024 * 1024;
        u16* h1_b = P_b;

        transpose_cvt<<<dim3(32, 16), dim3(32, 8), 0, stream>>>(W1, W1t, 512, 1024);
        transpose_cvt<<<dim3(32, 32), dim3(32, 8), 0, stream>>>(W2, W2t, 1024, 1024);
        transpose_cvt<<<dim3(16, 32), dim3(32, 8), 0, stream>>>(W3, W3t, 1024, 512);

        for (int c = 0; c < 8; ++c) {
            const float* xc = x + (size_t)c * 4096 * DIN;
            u16*         hc = h + (size_t)c * 4096 * DH;
            gemm_bt_bias_relu<true ><<<dim3(32, 8), 256, 0, stream>>>(xc, W1t, b1, h1_b,
                                                                      4096, 1024, 512, 1);
            gemm_bt_bias_relu<false><<<dim3(32, 8), 256, 0, stream>>>(h1_b, W2t, b2, hc,
                                                                      4096, 1024, 1024, 1);
        }
        for (int b = 0; b < B_; ++b) {
            const u16* hb = h + (size_t)b * S_ * DH;
            transpose_b<<<dim3(32, 64, 1), dim3(32, 8), 0, stream>>>(hb, hT_b, 2048, 1024);
            score_a<<<dim3(16, 16, 1), 256, 0, stream>>>(hb, P_b);
            softmax_rows<<<512, 256, 0, stream>>>(P_b);
            pv_a<<<16 * 8, 256, 0, stream>>>(P_b, hT_b, ctx_b, 1);
            gemm_bt_bias_relu<false><<<dim3(16, 4), 256, 0, stream>>>(ctx_b, W3t, b3, o_b,
                                                                      2048, 512, 1024, 1);
            head_logsoftmax<<<512, 256, 0, stream>>>(o_b, W4, b4,
                                                     out + (size_t)b * S_ * DOUT);
        }
    }

    // pass-throughs (f32)
    size_t n_gv = (size_t)in_sizes[1], n_uv = (size_t)in_sizes[2];
    size_t o0 = (size_t)out_size - n_gv - n_uv;
    hipMemcpyAsync(out + o0,        gv, n_gv * 4, hipMemcpyDeviceToDevice, stream);
    hipMemcpyAsync(out + o0 + n_gv, uv, n_uv * 4, hipMemcpyDeviceToDevice, stream);
}